// Round 3
// baseline (279468.091 us; speedup 1.0000x reference)
//
#include <hip/hip_runtime.h>
#include <hip/hip_bf16.h>
#include <stdint.h>

typedef __attribute__((ext_vector_type(8))) short short8;
typedef __attribute__((ext_vector_type(4))) float f32x4;

__device__ __forceinline__ unsigned short f2bf(float f) {
  union { float f; unsigned u; } v; v.f = f;
  unsigned r = v.u + 0x7FFFu + ((v.u >> 16) & 1u);
  return (unsigned short)(r >> 16);
}
__device__ __forceinline__ float bf2f(unsigned short h) {
  union { unsigned u; float f; } v; v.u = ((unsigned)h) << 16;
  return v.f;
}
__device__ __forceinline__ float sigm(float x) {
  x = fminf(fmaxf(x, -30.f), 30.f);
  return 1.f / (1.f + __expf(-x));
}
__device__ __forceinline__ float tanh_(float x) {
  x = fminf(fmaxf(x, -15.f), 15.f);
  float t = __expf(2.f * x);
  return (t - 1.f) / (t + 1.f);
}
__device__ __forceinline__ short8 pack8(float4 u, float4 v) {
  short8 r;
  r[0] = (short)f2bf(u.x); r[1] = (short)f2bf(u.y); r[2] = (short)f2bf(u.z); r[3] = (short)f2bf(u.w);
  r[4] = (short)f2bf(v.x); r[5] = (short)f2bf(v.y); r[6] = (short)f2bf(v.z); r[7] = (short)f2bf(v.w);
  return r;
}

// C[M,N] bf16 = A[M,K] f32 * B[N,K]^T f32 + bias[N].  M,N mult of 128, K mult of 32.
__global__ __launch_bounds__(256) void gemm_nt_bias(
    const float* __restrict__ A, const float* __restrict__ B,
    const float* __restrict__ bias, unsigned short* __restrict__ C,
    int M, int N, int K)
{
  __shared__ __align__(16) short As[128 * 32];
  __shared__ __align__(16) short Bs[128 * 32];
  const int tid = threadIdx.x;
  const int lane = tid & 63, w = tid >> 6;
  const int brow = blockIdx.x * 128, bcol = blockIdx.y * 128;
  const int wrow = (w & 1) * 64, wcol = (w >> 1) * 64;
  const int c16 = lane & 15, kg = lane >> 4;
  f32x4 acc[4][4];
#pragma unroll
  for (int m = 0; m < 4; m++)
#pragma unroll
    for (int n = 0; n < 4; n++) { f32x4 z = {0.f, 0.f, 0.f, 0.f}; acc[m][n] = z; }

  const int lrow = tid >> 1, lk = (tid & 1) * 16;
  const float* ap = A + (size_t)(brow + lrow) * K + lk;
  const float* bp = B + (size_t)(bcol + lrow) * K + lk;
  short* asw = &As[lrow * 32 + lk];
  short* bsw = &Bs[lrow * 32 + lk];

  for (int kb = 0; kb < K; kb += 32) {
    float4 a0 = *(const float4*)(ap + kb);
    float4 a1 = *(const float4*)(ap + kb + 4);
    float4 a2 = *(const float4*)(ap + kb + 8);
    float4 a3 = *(const float4*)(ap + kb + 12);
    float4 b0 = *(const float4*)(bp + kb);
    float4 b1 = *(const float4*)(bp + kb + 4);
    float4 b2 = *(const float4*)(bp + kb + 8);
    float4 b3 = *(const float4*)(bp + kb + 12);
    __syncthreads();
    *(short8*)asw = pack8(a0, a1);
    *(short8*)(asw + 8) = pack8(a2, a3);
    *(short8*)bsw = pack8(b0, b1);
    *(short8*)(bsw + 8) = pack8(b2, b3);
    __syncthreads();
    short8 af[4], bf[4];
#pragma unroll
    for (int m = 0; m < 4; m++) af[m] = *(const short8*)&As[(wrow + m * 16 + c16) * 32 + kg * 8];
#pragma unroll
    for (int n = 0; n < 4; n++) bf[n] = *(const short8*)&Bs[(wcol + n * 16 + c16) * 32 + kg * 8];
#pragma unroll
    for (int m = 0; m < 4; m++)
#pragma unroll
      for (int n = 0; n < 4; n++)
        acc[m][n] = __builtin_amdgcn_mfma_f32_16x16x32_bf16(af[m], bf[n], acc[m][n], 0, 0, 0);
  }
#pragma unroll
  for (int n = 0; n < 4; n++) {
    const int col = bcol + wcol + n * 16 + c16;
    const float bv = bias[col];
#pragma unroll
    for (int m = 0; m < 4; m++) {
#pragma unroll
      for (int i = 0; i < 4; i++) {
        const int row = brow + wrow + m * 16 + kg * 4 + i;
        C[(size_t)row * N + col] = f2bf(acc[m][n][i] + bv);
      }
    }
  }
}

// Encoder GRU scan: ONE workgroup (16 waves) per direction, all of Whh
// persistent in registers. Wave w owns full tiles 4w..4w+3 (192 VGPR) plus
// half of leftover tile 64+(w&7) (24 VGPR) => 216 VGPR of weights/wave.
// Per step: 2 barriers, LDS-only exchange. No atomics, no fences.
__global__ __launch_bounds__(1024) void enc_scan3(
    const float* __restrict__ WhhF, const float* __restrict__ bhhF,
    const float* __restrict__ WhhB, const float* __restrict__ bhhB,
    const unsigned short* __restrict__ Gf, const unsigned short* __restrict__ Gb,
    unsigned short* __restrict__ outputs, int L)
{
  const int dir = blockIdx.x;
  const float* Whh = dir ? WhhB : WhhF;
  const float* bhh = dir ? bhhB : bhhF;
  const unsigned short* G = dir ? Gb : Gf;
  const int tid = threadIdx.x, lane = tid & 63, w = tid >> 6;
  const int c16 = lane & 15, kg = lane >> 4;

  __shared__ __align__(16) unsigned short h_cur[384];
  __shared__ float gacc[1152];
  __shared__ float gpart[128];

  // full tiles
  short8 wf[4][12];
  float bb[4];
#pragma unroll
  for (int tt = 0; tt < 4; tt++) {
    const int jrow = (4 * w + tt) * 16 + c16;
    bb[tt] = bhh[jrow];
    const float* rowp = Whh + (size_t)jrow * 384 + kg * 8;
#pragma unroll
    for (int t = 0; t < 12; t++)
      wf[tt][t] = pack8(*(const float4*)(rowp + t * 32), *(const float4*)(rowp + t * 32 + 4));
  }
  // leftover half-tile: tile q = 64+(w&7), K-chunks [6*half, 6*half+6)
  const int q = 64 + (w & 7);
  const int half = w >> 3;
  const int jx = q * 16 + c16;
  const float bbx = (half == 0) ? bhh[jx] : 0.f;
  short8 wfx[6];
  {
    const float* rowp = Whh + (size_t)jx * 384 + (size_t)half * 192 + kg * 8;
#pragma unroll
    for (int u = 0; u < 6; u++)
      wfx[u] = pack8(*(const float4*)(rowp + u * 32), *(const float4*)(rowp + u * 32 + 4));
  }

  if (tid < 192) ((unsigned*)h_cur)[tid] = 0u;
  __syncthreads();
  float h_own = 0.f;  // state for combine threads (tid<384)

  for (int si = 0; si < L; ++si) {
    const int s = dir ? (L - 1 - si) : si;
    float gi0 = 0.f, gi1 = 0.f, gi2 = 0.f;
    if (tid < 384) {
      const size_t gb = (size_t)s * 1152 + tid;
      gi0 = bf2f(G[gb]);
      gi1 = bf2f(G[gb + 384]);
      gi2 = bf2f(G[gb + 768]);
    }
    f32x4 acc[4], accx;
#pragma unroll
    for (int tt = 0; tt < 4; tt++) { f32x4 t = {bb[tt], bb[tt], bb[tt], bb[tt]}; acc[tt] = t; }
    { f32x4 t = {bbx, bbx, bbx, bbx}; accx = t; }
#pragma unroll
    for (int t = 0; t < 12; t++) {
      short8 a = *(const short8*)&h_cur[t * 32 + kg * 8];
#pragma unroll
      for (int tt = 0; tt < 4; tt++)
        acc[tt] = __builtin_amdgcn_mfma_f32_16x16x32_bf16(a, wf[tt][t], acc[tt], 0, 0, 0);
      if (t >= 6 * half && t < 6 * half + 6)
        accx = __builtin_amdgcn_mfma_f32_16x16x32_bf16(a, wfx[t % 6], accx, 0, 0, 0);
    }
    if (kg == 0) {
#pragma unroll
      for (int tt = 0; tt < 4; tt++)
        gacc[(4 * w + tt) * 16 + c16] = acc[tt][0];
      if (half == 0) gacc[jx] = accx[0];
      else gpart[(w & 7) * 16 + c16] = accx[0];
    }
    __syncthreads();
    if (tid < 384) {
      float np = gacc[768 + tid];
      if (tid >= 256) np += gpart[tid - 256];
      const float r = sigm(gi0 + gacc[tid]);
      const float z = sigm(gi1 + gacc[384 + tid]);
      const float n = tanh_(gi2 + r * np);
      h_own = (1.f - z) * n + z * h_own;
      const unsigned short hb = f2bf(h_own);
      h_cur[tid] = hb;
      outputs[(size_t)s * 768 + dir * 384 + tid] = hb;
    }
    __syncthreads();
  }
}

// Decoder GRU scan: 6 WGs x 16 waves. WG j owns tiles T with T%6==j (24 of 144),
// so its r/z/n tiles match its 128 h-rows (combine WG-local). h exchanged via
// relaxed agent-scope u32 atomics (ring of 2) + per-step counter flag.
__global__ __launch_bounds__(1024) void dec_scan3(
    const float* __restrict__ Whh, const float* __restrict__ bhh,
    const unsigned short* __restrict__ Gd, const unsigned short* __restrict__ outputs,
    unsigned short* __restrict__ dechs, unsigned int* __restrict__ hx,
    int* __restrict__ ctrD, int L, int Ksteps)
{
  const int j = blockIdx.x;  // 0..5
  const int tid = threadIdx.x, lane = tid & 63, w = tid >> 6;
  const int c16 = lane & 15, kg = lane >> 4;
  const int nt = (w < 8) ? 2 : 1;
  const int n0 = (w < 8) ? (2 * w) : (8 + w);

  __shared__ __align__(16) unsigned short h_cur[768];
  __shared__ float gacc[384];

  short8 wf[2][24];
  float bb[2];
#pragma unroll
  for (int tt = 0; tt < 2; tt++) {
    if (tt < nt) {
      const int T = j + 6 * (n0 + tt);
      const int row = T * 16 + c16;
      bb[tt] = bhh[row];
      const float* rowp = Whh + (size_t)row * 768 + kg * 8;
#pragma unroll
      for (int t = 0; t < 24; t++)
        wf[tt][t] = pack8(*(const float4*)(rowp + t * 32), *(const float4*)(rowp + t * 32 + 4));
    }
  }
  const unsigned short* outLast = outputs + (size_t)(L - 1) * 768;
  const int m = tid >> 4, cc = tid & 15;
  const int hrow = (j + 6 * m) * 16 + cc;  // valid for tid<128
  float h_own = (tid < 128) ? bf2f(outLast[hrow]) : 0.f;

  if (tid < 384) ((unsigned*)h_cur)[tid] = ((const unsigned*)outLast)[tid];
  __syncthreads();

  for (int s = 0; s < Ksteps; ++s) {
    float gi0 = 0.f, gi1 = 0.f, gi2 = 0.f;
    if (tid < 128) {
      const size_t gb = (size_t)s * 2304 + hrow;
      gi0 = bf2f(Gd[gb]);
      gi1 = bf2f(Gd[gb + 768]);
      gi2 = bf2f(Gd[gb + 1536]);
    }
    f32x4 acc[2];
#pragma unroll
    for (int tt = 0; tt < 2; tt++) { f32x4 t = {bb[tt], bb[tt], bb[tt], bb[tt]}; acc[tt] = t; }
#pragma unroll
    for (int t = 0; t < 24; t++) {
      short8 a = *(const short8*)&h_cur[t * 32 + kg * 8];
#pragma unroll
      for (int tt = 0; tt < 2; tt++)
        if (tt < nt)
          acc[tt] = __builtin_amdgcn_mfma_f32_16x16x32_bf16(a, wf[tt][t], acc[tt], 0, 0, 0);
    }
    if (kg == 0) {
#pragma unroll
      for (int tt = 0; tt < 2; tt++)
        if (tt < nt) gacc[(n0 + tt) * 16 + c16] = acc[tt][0];
    }
    __syncthreads();
    unsigned int* slot = hx + (s & 1) * 384;
    if (tid < 128) {
      const float r = sigm(gi0 + gacc[tid]);
      const float z = sigm(gi1 + gacc[128 + tid]);
      const float n = tanh_(gi2 + r * gacc[256 + tid]);
      h_own = (1.f - z) * n + z * h_own;
      const unsigned short hb = f2bf(h_own);
      dechs[(size_t)s * 768 + hrow] = hb;
      const unsigned partner = (unsigned)__shfl_down((int)hb, 1) & 0xFFFFu;
      if ((cc & 1) == 0)
        __hip_atomic_store(&slot[hrow >> 1], ((unsigned)hb) | (partner << 16),
                           __ATOMIC_RELAXED, __HIP_MEMORY_SCOPE_AGENT);
    }
    __syncthreads();  // per-wave vmcnt drain before barrier => stores done
    if (tid == 0)
      __hip_atomic_fetch_add(&ctrD[s], 1, __ATOMIC_RELAXED, __HIP_MEMORY_SCOPE_AGENT);
    if (s + 1 < Ksteps) {
      if (tid == 0) {
        while (__hip_atomic_load(&ctrD[s], __ATOMIC_RELAXED, __HIP_MEMORY_SCOPE_AGENT) < 6)
          __builtin_amdgcn_s_sleep(2);
      }
      __syncthreads();
      if (tid < 384) {
        unsigned v = __hip_atomic_load(&slot[tid], __ATOMIC_RELAXED, __HIP_MEMORY_SCOPE_AGENT);
        ((unsigned*)h_cur)[tid] = v;
      }
      __syncthreads();
    }
  }
}

__global__ void gather_dec(const unsigned short* __restrict__ outputs,
                           const int* __restrict__ breaks,
                           float* __restrict__ din, int L)
{
  const int b = blockIdx.x;
  const int start = b ? breaks[b - 1] : 0;
  const unsigned short* src = outputs + (size_t)start * 768;
  for (int d = threadIdx.x; d < 768; d += blockDim.x)
    din[(size_t)b * 768 + d] = bf2f(src[d]);
}

// C[M,N] f32 = A[M,K] bf16 * B[N,K]^T bf16 (scores = dechs . outputs^T)
__global__ __launch_bounds__(256) void gemm_score(
    const unsigned short* __restrict__ A, const unsigned short* __restrict__ B,
    float* __restrict__ C, int M, int N, int K)
{
  __shared__ __align__(16) short As[128 * 32];
  __shared__ __align__(16) short Bs[128 * 32];
  const int tid = threadIdx.x;
  const int lane = tid & 63, w = tid >> 6;
  const int brow = blockIdx.x * 128, bcol = blockIdx.y * 128;
  const int wrow = (w & 1) * 64, wcol = (w >> 1) * 64;
  const int c16 = lane & 15, kg = lane >> 4;
  f32x4 acc[4][4];
#pragma unroll
  for (int m = 0; m < 4; m++)
#pragma unroll
    for (int n = 0; n < 4; n++) { f32x4 z = {0.f, 0.f, 0.f, 0.f}; acc[m][n] = z; }

  const int lrow = tid >> 1, lk = (tid & 1) * 16;
  const unsigned short* ap = A + (size_t)(brow + lrow) * K + lk;
  const unsigned short* bp = B + (size_t)(bcol + lrow) * K + lk;
  short* asw = &As[lrow * 32 + lk];
  short* bsw = &Bs[lrow * 32 + lk];

  for (int kb = 0; kb < K; kb += 32) {
    short8 a0 = *(const short8*)(ap + kb);
    short8 a1 = *(const short8*)(ap + kb + 8);
    short8 b0 = *(const short8*)(bp + kb);
    short8 b1 = *(const short8*)(bp + kb + 8);
    __syncthreads();
    *(short8*)asw = a0;
    *(short8*)(asw + 8) = a1;
    *(short8*)bsw = b0;
    *(short8*)(bsw + 8) = b1;
    __syncthreads();
    short8 af[4], bf[4];
#pragma unroll
    for (int m = 0; m < 4; m++) af[m] = *(const short8*)&As[(wrow + m * 16 + c16) * 32 + kg * 8];
#pragma unroll
    for (int n = 0; n < 4; n++) bf[n] = *(const short8*)&Bs[(wcol + n * 16 + c16) * 32 + kg * 8];
#pragma unroll
    for (int m = 0; m < 4; m++)
#pragma unroll
      for (int n = 0; n < 4; n++)
        acc[m][n] = __builtin_amdgcn_mfma_f32_16x16x32_bf16(af[m], bf[n], acc[m][n], 0, 0, 0);
  }
#pragma unroll
  for (int n = 0; n < 4; n++) {
    const int col = bcol + wcol + n * 16 + c16;
#pragma unroll
    for (int m = 0; m < 4; m++) {
#pragma unroll
      for (int i = 0; i < 4; i++) {
        const int row = brow + wrow + m * 16 + kg * 4 + i;
        C[(size_t)row * N + col] = acc[m][n][i];
      }
    }
  }
}

// Masked logsumexp over scores[k][start..L) minus score at target.
__global__ __launch_bounds__(256) void loss2(
    const float* __restrict__ scores, const int* __restrict__ breaks,
    float* __restrict__ lossk, int L)
{
  const int k = blockIdx.x;
  const int start = k ? breaks[k - 1] : 0;
  const int target = breaks[k];
  const float* row = scores + (size_t)k * L;
  __shared__ float wm[4], wss[4];
  float m = -3.4e38f, ss = 0.f;
  for (int p = start + threadIdx.x; p < L; p += 256) {
    const float v = row[p];
    if (v > m) { ss = ss * __expf(m - v) + 1.f; m = v; }
    else ss += __expf(v - m);
  }
#pragma unroll
  for (int off = 32; off > 0; off >>= 1) {
    const float mo = __shfl_down(m, off);
    const float so = __shfl_down(ss, off);
    const float mn = fmaxf(m, mo);
    ss = ss * __expf(m - mn) + so * __expf(mo - mn);
    m = mn;
  }
  if ((threadIdx.x & 63) == 0) { wm[threadIdx.x >> 6] = m; wss[threadIdx.x >> 6] = ss; }
  __syncthreads();
  if (threadIdx.x == 0) {
    float M = wm[0], S = wss[0];
#pragma unroll
    for (int q = 1; q < 4; ++q) {
      const float mn = fmaxf(M, wm[q]);
      S = S * __expf(M - mn) + wss[q] * __expf(wm[q] - mn);
      M = mn;
    }
    lossk[k] = (M + __logf(S)) - row[target];
  }
}

__global__ void final_reduce(const float* __restrict__ lossk, float* __restrict__ out, int K)
{
  __shared__ float buf[256];
  float s = 0.f;
  for (int idx = threadIdx.x; idx < K; idx += 256) s += lossk[idx];
  buf[threadIdx.x] = s;
  __syncthreads();
  for (int off = 128; off > 0; off >>= 1) {
    if (threadIdx.x < off) buf[threadIdx.x] += buf[threadIdx.x + off];
    __syncthreads();
  }
  if (threadIdx.x == 0) out[0] = buf[0];
}

extern "C" void kernel_launch(void* const* d_in, const int* in_sizes, int n_in,
                              void* d_out, int out_size, void* d_ws, size_t ws_size,
                              hipStream_t stream)
{
  const float* emb  = (const float*)d_in[0];
  const float* wihF = (const float*)d_in[1];
  const float* whhF = (const float*)d_in[2];
  const float* bihF = (const float*)d_in[3];
  const float* bhhF = (const float*)d_in[4];
  const float* wihB = (const float*)d_in[5];
  const float* whhB = (const float*)d_in[6];
  const float* bihB = (const float*)d_in[7];
  const float* bhhB = (const float*)d_in[8];
  const float* dwih = (const float*)d_in[9];
  const float* dwhh = (const float*)d_in[10];
  const float* dbih = (const float*)d_in[11];
  const float* dbhh = (const float*)d_in[12];
  const int*   brks = (const int*)d_in[13];
  const int L = in_sizes[0] / 768;
  const int K = in_sizes[13];

  auto pad = [](size_t b) { return (b + 255) & ~(size_t)255; };
  const size_t szG   = pad((size_t)L * 1152 * 2);
  const size_t szOut = pad((size_t)L * 768 * 2);
  const size_t szGd  = pad((size_t)K * 2304 * 2);
  const size_t szDin = pad((size_t)K * 768 * 4);
  const size_t szDhs = pad((size_t)K * 768 * 2);
  const size_t szLk  = pad((size_t)K * 4);
  const size_t szHx  = pad(2 * 384 * 4);
  const size_t szCtr = pad((size_t)K * 4);

  char* ws = (char*)d_ws;
  size_t off = 0;
  auto carve = [&](size_t bytes) -> char* { char* p = ws + off; off += bytes; return p; };
  unsigned short* Gf   = (unsigned short*)carve(szG);
  unsigned short* Gb   = (unsigned short*)carve(szG);
  unsigned short* outs = (unsigned short*)carve(szOut);
  unsigned short* Gd   = (unsigned short*)carve(szGd);
  float*          din  = (float*)carve(szDin);
  unsigned short* dhs  = (unsigned short*)carve(szDhs);
  float*          lk   = (float*)carve(szLk);
  unsigned int*   hx   = (unsigned int*)carve(szHx);
  int*            ctrD = (int*)carve(szCtr);
  float* scores = (float*)Gf;  // alias: Gf dead after enc_scan3; K*L*4 <= szG

  hipMemsetAsync(ctrD, 0, (size_t)K * 4, stream);

  gemm_nt_bias<<<dim3(L / 128, 9), 256, 0, stream>>>(emb, wihF, bihF, Gf, L, 1152, 768);
  gemm_nt_bias<<<dim3(L / 128, 9), 256, 0, stream>>>(emb, wihB, bihB, Gb, L, 1152, 768);
  enc_scan3<<<2, 1024, 0, stream>>>(whhF, bhhF, whhB, bhhB, Gf, Gb, outs, L);
  gather_dec<<<K, 256, 0, stream>>>(outs, brks, din, L);
  gemm_nt_bias<<<dim3(K / 128, 18), 256, 0, stream>>>(din, dwih, dbih, Gd, K, 2304, 768);
  dec_scan3<<<6, 1024, 0, stream>>>(dwhh, dbhh, Gd, outs, dhs, hx, ctrD, L, K);
  gemm_score<<<dim3(K / 128, L / 128), 256, 0, stream>>>(dhs, outs, scores, K, L, 768);
  loss2<<<K, 256, 0, stream>>>(scores, brks, lk, L);
  final_reduce<<<1, 256, 0, stream>>>(lk, (float*)d_out, K);
}

// Round 4
// 40014.218 us; speedup vs baseline: 6.9842x; 6.9842x over previous
//
#include <hip/hip_runtime.h>
#include <hip/hip_bf16.h>
#include <stdint.h>

typedef __attribute__((ext_vector_type(8))) short short8;
typedef __attribute__((ext_vector_type(4))) float f32x4;

__device__ __forceinline__ unsigned short f2bf(float f) {
  union { float f; unsigned u; } v; v.f = f;
  unsigned r = v.u + 0x7FFFu + ((v.u >> 16) & 1u);
  return (unsigned short)(r >> 16);
}
__device__ __forceinline__ float bf2f(unsigned short h) {
  union { unsigned u; float f; } v; v.u = ((unsigned)h) << 16;
  return v.f;
}
__device__ __forceinline__ float sigm(float x) {
  x = fminf(fmaxf(x, -30.f), 30.f);
  return 1.f / (1.f + __expf(-x));
}
__device__ __forceinline__ float tanh_(float x) {
  x = fminf(fmaxf(x, -15.f), 15.f);
  float t = __expf(2.f * x);
  return (t - 1.f) / (t + 1.f);
}
__device__ __forceinline__ short8 pack8(float4 u, float4 v) {
  short8 r;
  r[0] = (short)f2bf(u.x); r[1] = (short)f2bf(u.y); r[2] = (short)f2bf(u.z); r[3] = (short)f2bf(u.w);
  r[4] = (short)f2bf(v.x); r[5] = (short)f2bf(v.y); r[6] = (short)f2bf(v.z); r[7] = (short)f2bf(v.w);
  return r;
}

// MFMA with B operand pinned to AGPRs (can't be spilled/rematerialized by RA).
#define MFMA_AB(acc, a, b) \
  asm("v_mfma_f32_16x16x32_bf16 %0, %1, %2, %0" : "+v"(acc) : "v"(a), "a"(b))

// C[M,N] bf16 = A[M,K] f32 * B[N,K]^T f32 + bias[N].  M,N mult of 128, K mult of 32.
__global__ __launch_bounds__(256) void gemm_nt_bias(
    const float* __restrict__ A, const float* __restrict__ B,
    const float* __restrict__ bias, unsigned short* __restrict__ C,
    int M, int N, int K)
{
  __shared__ __align__(16) short As[128 * 32];
  __shared__ __align__(16) short Bs[128 * 32];
  const int tid = threadIdx.x;
  const int lane = tid & 63, w = tid >> 6;
  const int brow = blockIdx.x * 128, bcol = blockIdx.y * 128;
  const int wrow = (w & 1) * 64, wcol = (w >> 1) * 64;
  const int c16 = lane & 15, kg = lane >> 4;
  f32x4 acc[4][4];
#pragma unroll
  for (int m = 0; m < 4; m++)
#pragma unroll
    for (int n = 0; n < 4; n++) { f32x4 z = {0.f, 0.f, 0.f, 0.f}; acc[m][n] = z; }

  const int lrow = tid >> 1, lk = (tid & 1) * 16;
  const float* ap = A + (size_t)(brow + lrow) * K + lk;
  const float* bp = B + (size_t)(bcol + lrow) * K + lk;
  short* asw = &As[lrow * 32 + lk];
  short* bsw = &Bs[lrow * 32 + lk];

  for (int kb = 0; kb < K; kb += 32) {
    float4 a0 = *(const float4*)(ap + kb);
    float4 a1 = *(const float4*)(ap + kb + 4);
    float4 a2 = *(const float4*)(ap + kb + 8);
    float4 a3 = *(const float4*)(ap + kb + 12);
    float4 b0 = *(const float4*)(bp + kb);
    float4 b1 = *(const float4*)(bp + kb + 4);
    float4 b2 = *(const float4*)(bp + kb + 8);
    float4 b3 = *(const float4*)(bp + kb + 12);
    __syncthreads();
    *(short8*)asw = pack8(a0, a1);
    *(short8*)(asw + 8) = pack8(a2, a3);
    *(short8*)bsw = pack8(b0, b1);
    *(short8*)(bsw + 8) = pack8(b2, b3);
    __syncthreads();
    short8 af[4], bf[4];
#pragma unroll
    for (int m = 0; m < 4; m++) af[m] = *(const short8*)&As[(wrow + m * 16 + c16) * 32 + kg * 8];
#pragma unroll
    for (int n = 0; n < 4; n++) bf[n] = *(const short8*)&Bs[(wcol + n * 16 + c16) * 32 + kg * 8];
#pragma unroll
    for (int m = 0; m < 4; m++)
#pragma unroll
      for (int n = 0; n < 4; n++)
        acc[m][n] = __builtin_amdgcn_mfma_f32_16x16x32_bf16(af[m], bf[n], acc[m][n], 0, 0, 0);
  }
#pragma unroll
  for (int n = 0; n < 4; n++) {
    const int col = bcol + wcol + n * 16 + c16;
    const float bv = bias[col];
#pragma unroll
    for (int m = 0; m < 4; m++) {
#pragma unroll
      for (int i = 0; i < 4; i++) {
        const int row = brow + wrow + m * 16 + kg * 4 + i;
        C[(size_t)row * N + col] = f2bf(acc[m][n][i] + bv);
      }
    }
  }
}

// Encoder GRU scan: per direction 3 WGs x 8 waves. Wave w holds the gate-triple
// for h-rows [128r+16w, +16): 3 x 12 B-fragments = 144 AGPRs (inline-asm "a").
// Cross-WG h exchange: agent-scope atomics, double-buffered slot + step counter.
__global__ __launch_bounds__(512) __attribute__((amdgpu_waves_per_eu(2, 2)))
void enc_scan4(
    const float* __restrict__ WhhF, const float* __restrict__ bhhF,
    const float* __restrict__ WhhB, const float* __restrict__ bhhB,
    const unsigned short* __restrict__ Gf, const unsigned short* __restrict__ Gb,
    unsigned short* __restrict__ outputs, unsigned int* __restrict__ hxE,
    int* __restrict__ ctrE, int L)
{
  const int dir = blockIdx.x & 1;
  const int r = blockIdx.x >> 1;  // 0..2
  const float* Whh = dir ? WhhB : WhhF;
  const float* bhh = dir ? bhhB : bhhF;
  const unsigned short* G = dir ? Gb : Gf;
  unsigned int* hx = hxE + dir * 384;       // [2][192] u32 per dir
  int* ctr = ctrE + (size_t)dir * L;

  const int tid = threadIdx.x, lane = tid & 63, w = tid >> 6;
  const int c16 = lane & 15, kg = lane >> 4;

  __shared__ __align__(16) unsigned short h_cur[384];
  __shared__ float gacc[3 * 128];

  // Load this wave's weight fragments (rows hr, gates 0..2; K=384 -> 12 chunks).
  const int hr = 128 * r + 16 * w + c16;
  short8 wp0[12], wp1[12], wp2[12];
  {
    const float* p0 = Whh + (size_t)(0 * 384 + hr) * 384 + kg * 8;
    const float* p1 = Whh + (size_t)(1 * 384 + hr) * 384 + kg * 8;
    const float* p2 = Whh + (size_t)(2 * 384 + hr) * 384 + kg * 8;
#pragma unroll
    for (int t = 0; t < 12; t++) {
      wp0[t] = pack8(*(const float4*)(p0 + t * 32), *(const float4*)(p0 + t * 32 + 4));
      wp1[t] = pack8(*(const float4*)(p1 + t * 32), *(const float4*)(p1 + t * 32 + 4));
      wp2[t] = pack8(*(const float4*)(p2 + t * 32), *(const float4*)(p2 + t * 32 + 4));
    }
  }
  const int hrow = 128 * r + tid;  // combine-thread row (tid<128)
  float bb0 = 0.f, bb1 = 0.f, bb2 = 0.f;
  if (tid < 128) { bb0 = bhh[hrow]; bb1 = bhh[384 + hrow]; bb2 = bhh[768 + hrow]; }
  float h_own = 0.f;
  if (tid < 192) ((unsigned*)h_cur)[tid] = 0u;
  __syncthreads();

  for (int si = 0; si < L; ++si) {
    const int s = dir ? (L - 1 - si) : si;
    float gi0 = 0.f, gi1 = 0.f, gi2 = 0.f;
    if (tid < 128) {  // prefetch gi before the poll to hide L2/HBM latency
      const size_t gb = (size_t)s * 1152 + hrow;
      gi0 = bf2f(G[gb]); gi1 = bf2f(G[gb + 384]); gi2 = bf2f(G[gb + 768]);
    }
    if (si > 0) {
      if (tid == 0)
        while (__hip_atomic_load(&ctr[si - 1], __ATOMIC_ACQUIRE, __HIP_MEMORY_SCOPE_AGENT) < 3)
          __builtin_amdgcn_s_sleep(1);
      __syncthreads();
      if (tid < 192) {
        unsigned v = __hip_atomic_load(&hx[((si - 1) & 1) * 192 + tid],
                                       __ATOMIC_RELAXED, __HIP_MEMORY_SCOPE_AGENT);
        ((unsigned*)h_cur)[tid] = v;
      }
      __syncthreads();
    }
    f32x4 acc0 = {0.f, 0.f, 0.f, 0.f}, acc1 = {0.f, 0.f, 0.f, 0.f}, acc2 = {0.f, 0.f, 0.f, 0.f};
#pragma unroll
    for (int t = 0; t < 12; t++) {
      short8 a = *(const short8*)&h_cur[t * 32 + kg * 8];
      MFMA_AB(acc0, a, wp0[t]);
      MFMA_AB(acc1, a, wp1[t]);
      MFMA_AB(acc2, a, wp2[t]);
    }
    asm volatile("s_nop 7\n\ts_nop 7");  // MFMA-write -> read hazard (opaque asm)
    if (kg == 0) {
      gacc[0 * 128 + 16 * w + c16] = acc0[0];
      gacc[1 * 128 + 16 * w + c16] = acc1[0];
      gacc[2 * 128 + 16 * w + c16] = acc2[0];
    }
    __syncthreads();
    if (tid < 128) {
      const float rg = sigm(gi0 + bb0 + gacc[tid]);
      const float zg = sigm(gi1 + bb1 + gacc[128 + tid]);
      const float ng = tanh_(gi2 + bb2 + rg * gacc[256 + tid]);
      h_own = (1.f - zg) * ng + zg * h_own;
      const unsigned short hb = f2bf(h_own);
      outputs[(size_t)s * 768 + dir * 384 + hrow] = hb;
      const unsigned partner = (unsigned)__shfl_down((int)hb, 1) & 0xFFFFu;
      if ((tid & 1) == 0)
        __hip_atomic_store(&hx[(si & 1) * 192 + 64 * r + (tid >> 1)],
                           ((unsigned)hb & 0xFFFFu) | (partner << 16),
                           __ATOMIC_RELAXED, __HIP_MEMORY_SCOPE_AGENT);
    }
    __syncthreads();  // drains vmcnt: h stores complete before flag
    if (tid == 0)
      __hip_atomic_fetch_add(&ctr[si], 1, __ATOMIC_RELEASE, __HIP_MEMORY_SCOPE_AGENT);
  }
}

// Decoder GRU scan: 12 WGs x 8 waves. WG j owns h-rows [64j,64j+64).
// Wave w owns 3 pieces p=3w+e: half=p&1, g=(p>>1)>>2, q=(p>>1)&3 -> rows
// g*768+64j+16q, K-range [384*half, +384) = 12 chunks = 48 AGPRs; 144 total.
__global__ __launch_bounds__(512) __attribute__((amdgpu_waves_per_eu(2, 2)))
void dec_scan4(
    const float* __restrict__ Whh, const float* __restrict__ bhh,
    const unsigned short* __restrict__ Gd, const unsigned short* __restrict__ outputs,
    unsigned short* __restrict__ dechs, unsigned int* __restrict__ hxD,
    int* __restrict__ ctrD, int L, int Ksteps)
{
  const int j = blockIdx.x;  // 0..11
  const int tid = threadIdx.x, lane = tid & 63, w = tid >> 6;
  const int c16 = lane & 15, kg = lane >> 4;

  __shared__ __align__(16) unsigned short h_cur[768];
  __shared__ float gacc[3 * 64 * 2];

  int hf[3], gg[3], qq[3];
  short8 wpc0[12], wpc1[12], wpc2[12];
#pragma unroll
  for (int e = 0; e < 3; e++) {
    const int p = 3 * w + e;
    hf[e] = p & 1;
    gg[e] = (p >> 1) >> 2;
    qq[e] = (p >> 1) & 3;
  }
  {
    const float* rp0 = Whh + (size_t)(gg[0] * 768 + 64 * j + 16 * qq[0] + c16) * 768 + hf[0] * 384 + kg * 8;
    const float* rp1 = Whh + (size_t)(gg[1] * 768 + 64 * j + 16 * qq[1] + c16) * 768 + hf[1] * 384 + kg * 8;
    const float* rp2 = Whh + (size_t)(gg[2] * 768 + 64 * j + 16 * qq[2] + c16) * 768 + hf[2] * 384 + kg * 8;
#pragma unroll
    for (int t = 0; t < 12; t++) {
      wpc0[t] = pack8(*(const float4*)(rp0 + t * 32), *(const float4*)(rp0 + t * 32 + 4));
      wpc1[t] = pack8(*(const float4*)(rp1 + t * 32), *(const float4*)(rp1 + t * 32 + 4));
      wpc2[t] = pack8(*(const float4*)(rp2 + t * 32), *(const float4*)(rp2 + t * 32 + 4));
    }
  }
  const unsigned short* outLast = outputs + (size_t)(L - 1) * 768;
  const int hrow = 64 * j + tid;  // combine row (tid<64)
  float bb0 = 0.f, bb1 = 0.f, bb2 = 0.f, h_own = 0.f;
  if (tid < 64) {
    bb0 = bhh[hrow]; bb1 = bhh[768 + hrow]; bb2 = bhh[1536 + hrow];
    h_own = bf2f(outLast[hrow]);
  }
  if (tid < 384) ((unsigned*)h_cur)[tid] = ((const unsigned*)outLast)[tid];
  __syncthreads();

  for (int s = 0; s < Ksteps; ++s) {
    float gi0 = 0.f, gi1 = 0.f, gi2 = 0.f;
    if (tid < 64) {
      const size_t gb = (size_t)s * 2304 + hrow;
      gi0 = bf2f(Gd[gb]); gi1 = bf2f(Gd[gb + 768]); gi2 = bf2f(Gd[gb + 1536]);
    }
    if (s > 0) {
      if (tid == 0)
        while (__hip_atomic_load(&ctrD[s - 1], __ATOMIC_ACQUIRE, __HIP_MEMORY_SCOPE_AGENT) < 12)
          __builtin_amdgcn_s_sleep(1);
      __syncthreads();
      if (tid < 384) {
        unsigned v = __hip_atomic_load(&hxD[((s - 1) & 1) * 384 + tid],
                                       __ATOMIC_RELAXED, __HIP_MEMORY_SCOPE_AGENT);
        ((unsigned*)h_cur)[tid] = v;
      }
      __syncthreads();
    }
    f32x4 acc0 = {0.f, 0.f, 0.f, 0.f}, acc1 = {0.f, 0.f, 0.f, 0.f}, acc2 = {0.f, 0.f, 0.f, 0.f};
#pragma unroll
    for (int t = 0; t < 12; t++) {
      short8 a0 = *(const short8*)&h_cur[hf[0] * 384 + t * 32 + kg * 8];
      MFMA_AB(acc0, a0, wpc0[t]);
      short8 a1 = *(const short8*)&h_cur[hf[1] * 384 + t * 32 + kg * 8];
      MFMA_AB(acc1, a1, wpc1[t]);
      short8 a2 = *(const short8*)&h_cur[hf[2] * 384 + t * 32 + kg * 8];
      MFMA_AB(acc2, a2, wpc2[t]);
    }
    asm volatile("s_nop 7\n\ts_nop 7");
    if (kg == 0) {
      gacc[(gg[0] * 64 + 16 * qq[0] + c16) * 2 + hf[0]] = acc0[0];
      gacc[(gg[1] * 64 + 16 * qq[1] + c16) * 2 + hf[1]] = acc1[0];
      gacc[(gg[2] * 64 + 16 * qq[2] + c16) * 2 + hf[2]] = acc2[0];
    }
    __syncthreads();
    if (tid < 64) {
      const float s0 = gacc[(0 * 64 + tid) * 2] + gacc[(0 * 64 + tid) * 2 + 1];
      const float s1 = gacc[(1 * 64 + tid) * 2] + gacc[(1 * 64 + tid) * 2 + 1];
      const float s2 = gacc[(2 * 64 + tid) * 2] + gacc[(2 * 64 + tid) * 2 + 1];
      const float rg = sigm(gi0 + bb0 + s0);
      const float zg = sigm(gi1 + bb1 + s1);
      const float ng = tanh_(gi2 + bb2 + rg * s2);
      h_own = (1.f - zg) * ng + zg * h_own;
      const unsigned short hb = f2bf(h_own);
      dechs[(size_t)s * 768 + hrow] = hb;
      const unsigned partner = (unsigned)__shfl_down((int)hb, 1) & 0xFFFFu;
      if ((tid & 1) == 0)
        __hip_atomic_store(&hxD[(s & 1) * 384 + 32 * j + (tid >> 1)],
                           ((unsigned)hb & 0xFFFFu) | (partner << 16),
                           __ATOMIC_RELAXED, __HIP_MEMORY_SCOPE_AGENT);
    }
    __syncthreads();
    if (tid == 0)
      __hip_atomic_fetch_add(&ctrD[s], 1, __ATOMIC_RELEASE, __HIP_MEMORY_SCOPE_AGENT);
  }
}

__global__ void gather_dec(const unsigned short* __restrict__ outputs,
                           const int* __restrict__ breaks,
                           float* __restrict__ din, int L)
{
  const int b = blockIdx.x;
  const int start = b ? breaks[b - 1] : 0;
  const unsigned short* src = outputs + (size_t)start * 768;
  for (int d = threadIdx.x; d < 768; d += blockDim.x)
    din[(size_t)b * 768 + d] = bf2f(src[d]);
}

// C[M,N] f32 = A[M,K] bf16 * B[N,K]^T bf16 (scores = dechs . outputs^T)
__global__ __launch_bounds__(256) void gemm_score(
    const unsigned short* __restrict__ A, const unsigned short* __restrict__ B,
    float* __restrict__ C, int M, int N, int K)
{
  __shared__ __align__(16) short As[128 * 32];
  __shared__ __align__(16) short Bs[128 * 32];
  const int tid = threadIdx.x;
  const int lane = tid & 63, w = tid >> 6;
  const int brow = blockIdx.x * 128, bcol = blockIdx.y * 128;
  const int wrow = (w & 1) * 64, wcol = (w >> 1) * 64;
  const int c16 = lane & 15, kg = lane >> 4;
  f32x4 acc[4][4];
#pragma unroll
  for (int m = 0; m < 4; m++)
#pragma unroll
    for (int n = 0; n < 4; n++) { f32x4 z = {0.f, 0.f, 0.f, 0.f}; acc[m][n] = z; }

  const int lrow = tid >> 1, lk = (tid & 1) * 16;
  const unsigned short* ap = A + (size_t)(brow + lrow) * K + lk;
  const unsigned short* bp = B + (size_t)(bcol + lrow) * K + lk;
  short* asw = &As[lrow * 32 + lk];
  short* bsw = &Bs[lrow * 32 + lk];

  for (int kb = 0; kb < K; kb += 32) {
    short8 a0 = *(const short8*)(ap + kb);
    short8 a1 = *(const short8*)(ap + kb + 8);
    short8 b0 = *(const short8*)(bp + kb);
    short8 b1 = *(const short8*)(bp + kb + 8);
    __syncthreads();
    *(short8*)asw = a0;
    *(short8*)(asw + 8) = a1;
    *(short8*)bsw = b0;
    *(short8*)(bsw + 8) = b1;
    __syncthreads();
    short8 af[4], bf[4];
#pragma unroll
    for (int m = 0; m < 4; m++) af[m] = *(const short8*)&As[(wrow + m * 16 + c16) * 32 + kg * 8];
#pragma unroll
    for (int n = 0; n < 4; n++) bf[n] = *(const short8*)&Bs[(wcol + n * 16 + c16) * 32 + kg * 8];
#pragma unroll
    for (int m = 0; m < 4; m++)
#pragma unroll
      for (int n = 0; n < 4; n++)
        acc[m][n] = __builtin_amdgcn_mfma_f32_16x16x32_bf16(af[m], bf[n], acc[m][n], 0, 0, 0);
  }
#pragma unroll
  for (int n = 0; n < 4; n++) {
    const int col = bcol + wcol + n * 16 + c16;
#pragma unroll
    for (int m = 0; m < 4; m++) {
#pragma unroll
      for (int i = 0; i < 4; i++) {
        const int row = brow + wrow + m * 16 + kg * 4 + i;
        C[(size_t)row * N + col] = acc[m][n][i];
      }
    }
  }
}

// Masked logsumexp over scores[k][start..L) minus score at target.
__global__ __launch_bounds__(256) void loss2(
    const float* __restrict__ scores, const int* __restrict__ breaks,
    float* __restrict__ lossk, int L)
{
  const int k = blockIdx.x;
  const int start = k ? breaks[k - 1] : 0;
  const int target = breaks[k];
  const float* row = scores + (size_t)k * L;
  __shared__ float wm[4], wss[4];
  float m = -3.4e38f, ss = 0.f;
  for (int p = start + threadIdx.x; p < L; p += 256) {
    const float v = row[p];
    if (v > m) { ss = ss * __expf(m - v) + 1.f; m = v; }
    else ss += __expf(v - m);
  }
#pragma unroll
  for (int off = 32; off > 0; off >>= 1) {
    const float mo = __shfl_down(m, off);
    const float so = __shfl_down(ss, off);
    const float mn = fmaxf(m, mo);
    ss = ss * __expf(m - mn) + so * __expf(mo - mn);
    m = mn;
  }
  if ((threadIdx.x & 63) == 0) { wm[threadIdx.x >> 6] = m; wss[threadIdx.x >> 6] = ss; }
  __syncthreads();
  if (threadIdx.x == 0) {
    float M = wm[0], S = wss[0];
#pragma unroll
    for (int q = 1; q < 4; ++q) {
      const float mn = fmaxf(M, wm[q]);
      S = S * __expf(M - mn) + wss[q] * __expf(wm[q] - mn);
      M = mn;
    }
    lossk[k] = (M + __logf(S)) - row[target];
  }
}

__global__ void final_reduce(const float* __restrict__ lossk, float* __restrict__ out, int K)
{
  __shared__ float buf[256];
  float s = 0.f;
  for (int idx = threadIdx.x; idx < K; idx += 256) s += lossk[idx];
  buf[threadIdx.x] = s;
  __syncthreads();
  for (int off = 128; off > 0; off >>= 1) {
    if (threadIdx.x < off) buf[threadIdx.x] += buf[threadIdx.x + off];
    __syncthreads();
  }
  if (threadIdx.x == 0) out[0] = buf[0];
}

extern "C" void kernel_launch(void* const* d_in, const int* in_sizes, int n_in,
                              void* d_out, int out_size, void* d_ws, size_t ws_size,
                              hipStream_t stream)
{
  const float* emb  = (const float*)d_in[0];
  const float* wihF = (const float*)d_in[1];
  const float* whhF = (const float*)d_in[2];
  const float* bihF = (const float*)d_in[3];
  const float* bhhF = (const float*)d_in[4];
  const float* wihB = (const float*)d_in[5];
  const float* whhB = (const float*)d_in[6];
  const float* bihB = (const float*)d_in[7];
  const float* bhhB = (const float*)d_in[8];
  const float* dwih = (const float*)d_in[9];
  const float* dwhh = (const float*)d_in[10];
  const float* dbih = (const float*)d_in[11];
  const float* dbhh = (const float*)d_in[12];
  const int*   brks = (const int*)d_in[13];
  const int L = in_sizes[0] / 768;
  const int K = in_sizes[13];

  auto pad = [](size_t b) { return (b + 255) & ~(size_t)255; };
  const size_t szG   = pad((size_t)L * 1152 * 2);
  const size_t szOut = pad((size_t)L * 768 * 2);
  const size_t szGd  = pad((size_t)K * 2304 * 2);
  const size_t szDin = pad((size_t)K * 768 * 4);
  const size_t szDhs = pad((size_t)K * 768 * 2);
  const size_t szLk  = pad((size_t)K * 4);
  const size_t szHx  = pad((2 * 2 * 192 + 2 * 384) * 4);  // hxE (2 dirs) + hxD
  const size_t ctrBytes = (2 * (size_t)L + K) * 4;        // ctrE + ctrD contiguous
  const size_t szCtr = pad(ctrBytes);

  char* ws = (char*)d_ws;
  size_t off = 0;
  auto carve = [&](size_t bytes) -> char* { char* p = ws + off; off += bytes; return p; };
  unsigned short* Gf   = (unsigned short*)carve(szG);
  unsigned short* Gb   = (unsigned short*)carve(szG);
  unsigned short* outs = (unsigned short*)carve(szOut);
  unsigned short* Gd   = (unsigned short*)carve(szGd);
  float*          din  = (float*)carve(szDin);
  unsigned short* dhs  = (unsigned short*)carve(szDhs);
  float*          lk   = (float*)carve(szLk);
  unsigned int*   hxE  = (unsigned int*)carve(szHx);
  unsigned int*   hxD  = hxE + 2 * 2 * 192;
  int*            ctrE = (int*)carve(szCtr);
  int*            ctrD = ctrE + 2 * (size_t)L;
  float* scores = (float*)Gf;  // alias: Gf dead after enc_scan4; K*L*4 <= szG

  hipMemsetAsync(ctrE, 0, ctrBytes, stream);

  gemm_nt_bias<<<dim3(L / 128, 9), 256, 0, stream>>>(emb, wihF, bihF, Gf, L, 1152, 768);
  gemm_nt_bias<<<dim3(L / 128, 9), 256, 0, stream>>>(emb, wihB, bihB, Gb, L, 1152, 768);
  enc_scan4<<<6, 512, 0, stream>>>(whhF, bhhF, whhB, bhhB, Gf, Gb, outs, hxE, ctrE, L);
  gather_dec<<<K, 256, 0, stream>>>(outs, brks, din, L);
  gemm_nt_bias<<<dim3(K / 128, 18), 256, 0, stream>>>(din, dwih, dbih, Gd, K, 2304, 768);
  dec_scan4<<<12, 512, 0, stream>>>(dwhh, dbhh, Gd, outs, dhs, hxD, ctrD, L, K);
  gemm_score<<<dim3(K / 128, L / 128), 256, 0, stream>>>(dhs, outs, scores, K, L, 768);
  loss2<<<K, 256, 0, stream>>>(scores, brks, lk, L);
  final_reduce<<<1, 256, 0, stream>>>(lk, (float*)d_out, K);
}